// Round 2
// baseline (48.534 us; speedup 1.0000x reference)
//
#include <hip/hip_runtime.h>
#include <math.h>

#define NPATCHES 10
#define PATCH    100
#define NSCALES  2
#define BB       8
#define HL       112
#define WL       112
#define HH       1024
#define WH       1024
#define HW       (HL*WL)        // 12544

__device__ __forceinline__ unsigned rotl32(unsigned x, unsigned r){
  return (x << r) | (x >> (32u - r));
}

// JAX threefry2x32 with key = (0, 1)  (jax.random.key(1))
__device__ __forceinline__ void threefry2x32_key01(unsigned x0, unsigned x1,
                                                   unsigned &o0, unsigned &o1){
  const unsigned ks0 = 0u;
  const unsigned ks1 = 1u;
  const unsigned ks2 = 0x1BD11BDAu ^ ks0 ^ ks1;
  unsigned a = x0 + ks0;
  unsigned b = x1 + ks1;
#define TF_RND(r) { a += b; b = rotl32(b, (r)); b ^= a; }
  TF_RND(13u) TF_RND(15u) TF_RND(26u) TF_RND(6u)
  a += ks1; b += ks2 + 1u;
  TF_RND(17u) TF_RND(29u) TF_RND(16u) TF_RND(24u)
  a += ks2; b += ks0 + 2u;
  TF_RND(13u) TF_RND(15u) TF_RND(26u) TF_RND(6u)
  a += ks0; b += ks1 + 3u;
  TF_RND(17u) TF_RND(29u) TF_RND(16u) TF_RND(24u)
  a += ks1; b += ks2 + 4u;
  TF_RND(13u) TF_RND(15u) TF_RND(26u) TF_RND(6u)
  a += ks2; b += ks0 + 5u;
#undef TF_RND
  o0 = a; o1 = b;
}

// One block per batch: sum -> perturbed scores in LDS -> 10x argmax ->
// emit small outputs + patch corners to workspace.
__global__ __launch_bounds__(1024)
void msp_topk_kernel(const float* __restrict__ ats_map,
                     const int*   __restrict__ ats_index,
                     const float* __restrict__ scales,
                     float* __restrict__ out,
                     int*   __restrict__ ws)
{
  __shared__ float vals[HW];
  __shared__ float rv[1024];
  __shared__ int   ri[64];
  __shared__ float s_sum;
  __shared__ int   sel[NPATCHES];

  const int b = blockIdx.x;
  const int t = threadIdx.x;
  const float* am = ats_map + (size_t)b * HW;

  // 1. per-batch attention sum (tree reduction, run once)
  float ps = 0.0f;
  for (int i = t; i < HW; i += 1024) ps += am[i];
  rv[t] = ps;
  __syncthreads();
  for (int s = 512; s > 0; s >>= 1){
    if (t < s) rv[t] += rv[t + s];
    __syncthreads();
  }
  if (t == 0) s_sum = rv[0];
  __syncthreads();
  const float S = s_sum;

  // 2. perturbed scores: log(att + 1e-10) + gumbel
  //    JAX partitionable threefry (default since 0.4.36): counter = 64-bit
  //    flat index i -> threefry2x32(key, (hi32(i), lo32(i))), bits = o0 ^ o1.
  for (int i = t; i < HW; i += 1024){
    const unsigned f = (unsigned)(b * HW + i);   // hi32 is 0 for our sizes
    unsigned o0, o1;
    threefry2x32_key01(0u, f, o0, o1);
    const unsigned bits = o0 ^ o1;
    const float u = __uint_as_float((bits >> 9) | 0x3f800000u) - 1.0f;
    const float g = -logf(-logf(u + 1e-10f) + 1e-10f);
    const float att = am[i] / S;
    vals[i] = logf(att + 1e-10f) + g;
  }
  __syncthreads();

  // 3. iterative argmax, tie-break lowest index (matches lax.top_k order)
  for (int n = 0; n < NPATCHES; ++n){
    float bv = -INFINITY; int bi = 0x7fffffff;
    for (int i = t; i < HW; i += 1024){
      const float v = vals[i];
      if (v > bv){ bv = v; bi = i; }
    }
    // wave-level reduce (64 lanes)
    for (int d = 32; d > 0; d >>= 1){
      const float v2 = __shfl_down(bv, d, 64);
      const int   i2 = __shfl_down(bi, d, 64);
      if (v2 > bv || (v2 == bv && i2 < bi)){ bv = v2; bi = i2; }
    }
    const int w = t >> 6;
    if ((t & 63) == 0){ rv[w] = bv; ri[w] = bi; }
    __syncthreads();
    if (t == 0){
      float fv = rv[0]; int fi = ri[0];
      for (int k = 1; k < 16; ++k){
        const float v2 = rv[k]; const int i2 = ri[k];
        if (v2 > fv || (v2 == fv && i2 < fi)){ fv = v2; fi = i2; }
      }
      sel[n] = fi;
      vals[fi] = -INFINITY;
    }
    __syncthreads();
  }

  // 4. small outputs + workspace corners
  if (t < NPATCHES){
    const int n = t;
    const int idx = sel[n];
    const float att = am[idx] / S;
    const int iy = idx / WL;
    const float sy = (float)iy;
    const float sx = (float)(idx - iy * WL);
    const int si = ats_index[(size_t)b * HW + idx];
    const float sc = scales[si];
    const float cy = sy / sc;
    const float cx = sx / sc;
    const float ratio = (float)(924.0 / 111.0);   // (HH-PATCH)/(HL-1), f64->f32 like ref
    int corner_y = (int)rintf(cy * ratio);        // rintf = round-half-even = jnp.round
    int corner_x = (int)rintf(cx * ratio);
    corner_y = min(max(corner_y, 0), HH - PATCH);
    corner_x = min(max(corner_x, 0), WH - PATCH);

    float* out_att = out + (size_t)BB * NPATCHES * PATCH * PATCH * 3;
    float* out_off = out_att + BB * NPATCHES;
    float* out_smp = out_off + BB * NPATCHES * 2;
    out_att[b * NPATCHES + n] = att;
    out_off[(b * NPATCHES + n) * 2 + 0] = 0.0f;   // RECEPTIVE_FIELD/2
    out_off[(b * NPATCHES + n) * 2 + 1] = 0.0f;
    out_smp[(b * NPATCHES + n) * 2 + 0] = cy;
    out_smp[(b * NPATCHES + n) * 2 + 1] = cx;

    int* w = ws + (b * NPATCHES + n) * 4;
    w[0] = corner_y; w[1] = corner_x; w[2] = si; w[3] = 0;
  }
}

// Patch gather: grid (80, 5); each block copies 20 rows of one patch.
__global__ __launch_bounds__(256)
void msp_gather_kernel(const float* __restrict__ x_highs,
                       const int*   __restrict__ ws,
                       float* __restrict__ out)
{
  const int pn    = blockIdx.x;   // b*NPATCHES + n
  const int chunk = blockIdx.y;   // 0..4
  const int t = threadIdx.x;
  const int* w = ws + pn * 4;
  const int cy = w[0], cx = w[1], s = w[2];
  const int b = pn / NPATCHES;
  const float* src = x_highs + (size_t)(s * BB + b) * HH * (WH * 3);
  float* dst = out + (size_t)pn * (PATCH * PATCH * 3);
  const int begin = chunk * 20 * PATCH * 3;
  const int end   = begin + 20 * PATCH * 3;
  for (int f = begin + t; f < end; f += 256){
    const int row = f / (PATCH * 3);
    const int col = f - row * (PATCH * 3);
    dst[f] = src[(size_t)(cy + row) * (WH * 3) + (size_t)cx * 3 + col];
  }
}

extern "C" void kernel_launch(void* const* d_in, const int* in_sizes, int n_in,
                              void* d_out, int out_size, void* d_ws, size_t ws_size,
                              hipStream_t stream)
{
  // setup_inputs order: x_lows(0, unused), x_highs(1), ats_map(2), ats_index(3), scales(4)
  const float* x_highs   = (const float*)d_in[1];
  const float* ats_map   = (const float*)d_in[2];
  const int*   ats_index = (const int*)d_in[3];
  const float* scales    = (const float*)d_in[4];
  float* out = (float*)d_out;
  int*   ws  = (int*)d_ws;

  hipLaunchKernelGGL(msp_topk_kernel, dim3(BB), dim3(1024), 0, stream,
                     ats_map, ats_index, scales, out, ws);
  hipLaunchKernelGGL(msp_gather_kernel, dim3(BB * NPATCHES, 5), dim3(256), 0, stream,
                     x_highs, ws, out);
}

// Round 3
// 40.608 us; speedup vs baseline: 1.1952x; 1.1952x over previous
//
#include <hip/hip_runtime.h>
#include <math.h>

#define NPATCHES 10
#define PATCH    100
#define NSCALES  2
#define BB       8
#define HL       112
#define WL       112
#define HH       1024
#define WH       1024
#define HW       (HL*WL)        // 12544
#define WSLICE   784            // HW / 16 waves
#define NW       16             // waves per block

__device__ __forceinline__ unsigned rotl32(unsigned x, unsigned r){
  return (x << r) | (x >> (32u - r));
}

// JAX threefry2x32 with key = (0, 1)  (jax.random.key(1))
__device__ __forceinline__ void threefry2x32_key01(unsigned x0, unsigned x1,
                                                   unsigned &o0, unsigned &o1){
  const unsigned ks0 = 0u;
  const unsigned ks1 = 1u;
  const unsigned ks2 = 0x1BD11BDAu ^ ks0 ^ ks1;
  unsigned a = x0 + ks0;
  unsigned b = x1 + ks1;
#define TF_RND(r) { a += b; b = rotl32(b, (r)); b ^= a; }
  TF_RND(13u) TF_RND(15u) TF_RND(26u) TF_RND(6u)
  a += ks1; b += ks2 + 1u;
  TF_RND(17u) TF_RND(29u) TF_RND(16u) TF_RND(24u)
  a += ks2; b += ks0 + 2u;
  TF_RND(13u) TF_RND(15u) TF_RND(26u) TF_RND(6u)
  a += ks0; b += ks1 + 3u;
  TF_RND(17u) TF_RND(29u) TF_RND(16u) TF_RND(24u)
  a += ks1; b += ks2 + 4u;
  TF_RND(13u) TF_RND(15u) TF_RND(26u) TF_RND(6u)
  a += ks2; b += ks0 + 5u;
#undef TF_RND
  o0 = a; o1 = b;
}

// One block per batch. Wave w owns slice [w*784, (w+1)*784); scores live in
// registers (<=13/lane). Per-wave top-10 via shuffle argmax + incremental
// removal (no barriers), then wave 0 merges 160 candidates.
__global__ __launch_bounds__(1024)
void msp_topk_kernel(const float* __restrict__ ats_map,
                     const int*   __restrict__ ats_index,
                     const float* __restrict__ scales,
                     float* __restrict__ out,
                     int*   __restrict__ ws)
{
  __shared__ float swv[NW];
  __shared__ float cand_v[NW * NPATCHES];
  __shared__ int   cand_i[NW * NPATCHES];
  __shared__ float s_sum;
  __shared__ int   sel[NPATCHES];

  const int b = blockIdx.x;
  const int t = threadIdx.x;
  const int w = t >> 6;       // wave 0..15
  const int l = t & 63;       // lane
  const int base = w * WSLICE;
  const float* am = ats_map + (size_t)b * HW;

  // 1. load slice into regs + per-batch sum
  float a[13];
  float ps = 0.0f;
  #pragma unroll
  for (int j = 0; j < 13; ++j){
    const int off = l + 64 * j;
    float x = 0.0f;
    if (off < WSLICE) x = am[base + off];
    a[j] = x;
    ps += x;
  }
  for (int d = 32; d > 0; d >>= 1) ps += __shfl_down(ps, d, 64);
  if (l == 0) swv[w] = ps;
  __syncthreads();
  if (t == 0){
    float s = 0.0f;
    for (int k = 0; k < NW; ++k) s += swv[k];
    s_sum = s;
  }
  __syncthreads();
  const float S = s_sum;

  // 2. perturbed scores in registers.
  //    JAX partitionable threefry: bits(i) = xor(threefry2x32(key,(0,i))).
  #pragma unroll
  for (int j = 0; j < 13; ++j){
    const int off = l + 64 * j;
    const int i = base + off;
    unsigned o0, o1;
    threefry2x32_key01(0u, (unsigned)(b * HW + i), o0, o1);
    const unsigned bits = o0 ^ o1;
    const float u = __uint_as_float((bits >> 9) | 0x3f800000u) - 1.0f;
    const float g = -logf(-logf(u + 1e-10f) + 1e-10f);
    const float att = a[j] / S;
    const float sc = logf(att + 1e-10f) + g;
    a[j] = (off < WSLICE) ? sc : -INFINITY;
  }

  // per-lane running max (smallest j wins ties -> smallest global index)
  float lv = -INFINITY; int lj = 0;
  #pragma unroll
  for (int j = 0; j < 13; ++j) if (a[j] > lv){ lv = a[j]; lj = j; }

  // 3. per-wave top-10, barrier-free
  for (int n = 0; n < NPATCHES; ++n){
    float bv = lv;
    int   bi = (lv == -INFINITY) ? 0x7fffffff : (base + l + 64 * lj);
    for (int d = 32; d > 0; d >>= 1){
      const float v2 = __shfl_down(bv, d, 64);
      const int   i2 = __shfl_down(bi, d, 64);
      if (v2 > bv || (v2 == bv && i2 < bi)){ bv = v2; bi = i2; }
    }
    bv = __shfl(bv, 0, 64);
    bi = __shfl(bi, 0, 64);
    if (l == 0){ cand_v[w * NPATCHES + n] = bv; cand_i[w * NPATCHES + n] = bi; }
    // removal: owner lane drops the winner and rescans its 13 regs
    const int rel = bi - base;
    if (bi != 0x7fffffff && (rel & 63) == l){
      a[rel >> 6] = -INFINITY;
      lv = -INFINITY; lj = 0;
      #pragma unroll
      for (int j = 0; j < 13; ++j) if (a[j] > lv){ lv = a[j]; lj = j; }
    }
  }
  __syncthreads();

  // 4. wave 0 merges 160 candidates -> global top-10
  if (w == 0){
    float mv[3]; int mi[3];
    #pragma unroll
    for (int c = 0; c < 3; ++c){
      const int id = l + 64 * c;
      if (id < NW * NPATCHES){ mv[c] = cand_v[id]; mi[c] = cand_i[id]; }
      else { mv[c] = -INFINITY; mi[c] = 0x7fffffff; }
    }
    float cv = -INFINITY; int ci = 0x7fffffff;
    #pragma unroll
    for (int c = 0; c < 3; ++c)
      if (mv[c] > cv || (mv[c] == cv && mi[c] < ci)){ cv = mv[c]; ci = mi[c]; }

    for (int n = 0; n < NPATCHES; ++n){
      float bv = cv; int bi = ci;
      for (int d = 32; d > 0; d >>= 1){
        const float v2 = __shfl_down(bv, d, 64);
        const int   i2 = __shfl_down(bi, d, 64);
        if (v2 > bv || (v2 == bv && i2 < bi)){ bv = v2; bi = i2; }
      }
      bv = __shfl(bv, 0, 64);
      bi = __shfl(bi, 0, 64);
      if (l == 0) sel[n] = bi;
      // removal from this lane's candidate regs
      bool had = false;
      #pragma unroll
      for (int c = 0; c < 3; ++c) if (mi[c] == bi && mv[c] == bv){ mv[c] = -INFINITY; had = true; }
      if (had){
        cv = -INFINITY; ci = 0x7fffffff;
        #pragma unroll
        for (int c = 0; c < 3; ++c)
          if (mv[c] > cv || (mv[c] == cv && mi[c] < ci)){ cv = mv[c]; ci = mi[c]; }
      }
    }
  }
  __syncthreads();

  // 5. small outputs + workspace corners
  if (t < NPATCHES){
    const int n = t;
    const int idx = sel[n];
    const float att = am[idx] / S;
    const int iy = idx / WL;
    const float sy = (float)iy;
    const float sx = (float)(idx - iy * WL);
    const int si = ats_index[(size_t)b * HW + idx];
    const float sc = scales[si];
    const float cy = sy / sc;
    const float cx = sx / sc;
    const float ratio = (float)(924.0 / 111.0);   // (HH-PATCH)/(HL-1), f64->f32 like ref
    int corner_y = (int)rintf(cy * ratio);        // rintf = round-half-even = jnp.round
    int corner_x = (int)rintf(cx * ratio);
    corner_y = min(max(corner_y, 0), HH - PATCH);
    corner_x = min(max(corner_x, 0), WH - PATCH);

    float* out_att = out + (size_t)BB * NPATCHES * PATCH * PATCH * 3;
    float* out_off = out_att + BB * NPATCHES;
    float* out_smp = out_off + BB * NPATCHES * 2;
    out_att[b * NPATCHES + n] = att;
    out_off[(b * NPATCHES + n) * 2 + 0] = 0.0f;   // RECEPTIVE_FIELD/2
    out_off[(b * NPATCHES + n) * 2 + 1] = 0.0f;
    out_smp[(b * NPATCHES + n) * 2 + 0] = cy;
    out_smp[(b * NPATCHES + n) * 2 + 1] = cx;

    int* wsp = ws + (b * NPATCHES + n) * 4;
    wsp[0] = corner_y; wsp[1] = corner_x; wsp[2] = si; wsp[3] = 0;
  }
}

// Patch gather: grid (80, 5); each block copies 20 rows of one patch.
__global__ __launch_bounds__(256)
void msp_gather_kernel(const float* __restrict__ x_highs,
                       const int*   __restrict__ ws,
                       float* __restrict__ out)
{
  const int pn    = blockIdx.x;   // b*NPATCHES + n
  const int chunk = blockIdx.y;   // 0..4
  const int t = threadIdx.x;
  const int* w = ws + pn * 4;
  const int cy = w[0], cx = w[1], s = w[2];
  const int b = pn / NPATCHES;
  const float* src = x_highs + (size_t)(s * BB + b) * HH * (WH * 3);
  float* dst = out + (size_t)pn * (PATCH * PATCH * 3);
  const int begin = chunk * 20 * PATCH * 3;
  const int end   = begin + 20 * PATCH * 3;
  for (int f = begin + t; f < end; f += 256){
    const int row = f / (PATCH * 3);
    const int col = f - row * (PATCH * 3);
    dst[f] = src[(size_t)(cy + row) * (WH * 3) + (size_t)cx * 3 + col];
  }
}

extern "C" void kernel_launch(void* const* d_in, const int* in_sizes, int n_in,
                              void* d_out, int out_size, void* d_ws, size_t ws_size,
                              hipStream_t stream)
{
  // setup_inputs order: x_lows(0, unused), x_highs(1), ats_map(2), ats_index(3), scales(4)
  const float* x_highs   = (const float*)d_in[1];
  const float* ats_map   = (const float*)d_in[2];
  const int*   ats_index = (const int*)d_in[3];
  const float* scales    = (const float*)d_in[4];
  float* out = (float*)d_out;
  int*   ws  = (int*)d_ws;

  hipLaunchKernelGGL(msp_topk_kernel, dim3(BB), dim3(1024), 0, stream,
                     ats_map, ats_index, scales, out, ws);
  hipLaunchKernelGGL(msp_gather_kernel, dim3(BB * NPATCHES, 5), dim3(256), 0, stream,
                     x_highs, ws, out);
}